// Round 4
// baseline (168.465 us; speedup 1.0000x reference)
//
#include <hip/hip_runtime.h>

#define N_SEL 8192
#define SUB_SZ 32
#define N_SUB 256
#define N_GRAPH 64
#define N_FULL 12288
#define E_RAW 262144
#define N_PERS 4
#define D 128
#define EPSILON 0.1f
#define LAMB1 0.5f

// ---- fused fill+merge geometry ----
#define CHUNK_FLOATS 16384                   // 64 KB LDS image per block
#define N_CHUNKS 9216                        // 12288*12288 / 16384
#define CAP 256                              // bucket capacity (expected max ~120)
#define WS_NEEDED ((size_t)N_CHUNKS * 4 + (size_t)N_CHUNKS * CAP * 8)

typedef float f4_t __attribute__((ext_vector_type(4)));

__global__ __launch_bounds__(256) void zero_counts_kernel(int* __restrict__ counts)
{
    int i = blockIdx.x * 256 + threadIdx.x;
    if (i < N_CHUNKS) counts[i] = 0;
}

__device__ __forceinline__ void bucket_append(
        int* counts, uint2* entries, long long flat, float v)
{
    int chunk = (int)(flat >> 14);           // /CHUNK_FLOATS
    int local = (int)(flat & (CHUNK_FLOATS - 1));
    int slot = atomicAdd(&counts[chunk], 1);
    if (slot < CAP)
        entries[(size_t)chunk * CAP + slot] = make_uint2((unsigned)local, __float_as_uint(v));
}

// Blocks [0,256): cosine subgraph blocks -> bucket entries.
// Blocks [256,1280): raw edges -> bucket entries (+0.5 each).
__global__ __launch_bounds__(256) void build_kernel(
        const float* __restrict__ x,
        const float* __restrict__ Wc,
        const float* __restrict__ sscore,
        const int*   __restrict__ smap,
        const int*   __restrict__ rei,
        int*   __restrict__ counts,
        uint2* __restrict__ entries)
{
    const int tid = threadIdx.x;

    if (blockIdx.x >= N_SUB) {
        int e = (blockIdx.x - N_SUB) * 256 + tid;
        long long r = rei[e];
        long long c = rei[E_RAW + e];
        bucket_append(counts, entries, r * (long long)N_FULL + c, 1.0f - LAMB1);
        return;
    }

    const int s    = blockIdx.x;
    const int base = s * SUB_SZ;

    __shared__ float xs[SUB_SZ][D + 1];
    __shared__ float w2[N_PERS][D];
    __shared__ float rnorm[N_PERS][SUB_SZ];
    __shared__ int   map_s[SUB_SZ];
    __shared__ float rowscore;

    for (int k = tid; k < SUB_SZ * D; k += 256) {
        int i = k >> 7;
        int d = k & (D - 1);
        xs[i][d] = x[(base + i) * D + d];
    }
    for (int k = tid; k < N_PERS * D; k += 256) {
        float w = Wc[k];
        ((float*)w2)[k] = w * w;
    }
    if (tid < SUB_SZ) map_s[tid] = smap[base + tid];
    if (tid == 0) {
        int g4 = (s >> 2) << 2;
        float sum = sscore[g4] + sscore[g4 + 1] + sscore[g4 + 2] + sscore[g4 + 3];
        rowscore = (sscore[s] / sum) * LAMB1;
    }
    __syncthreads();

    if (tid < N_PERS * SUB_SZ) {
        int p = tid >> 5;
        int i = tid & 31;
        float acc = 0.f;
        #pragma unroll 8
        for (int d = 0; d < D; ++d) {
            float v = xs[i][d];
            acc = fmaf(v * v, w2[p][d], acc);
        }
        rnorm[p][i] = 1.0f / fmaxf(sqrtf(acc), 1e-12f);
    }
    __syncthreads();

    for (int e = tid; e < SUB_SZ * SUB_SZ; e += 256) {
        int i = e >> 5;
        int j = e & 31;
        if (i == j) continue;
        float a0 = 0.f, a1 = 0.f, a2 = 0.f, a3 = 0.f;
        #pragma unroll 8
        for (int d = 0; d < D; ++d) {
            float prod = xs[i][d] * xs[j][d];
            a0 = fmaf(prod, w2[0][d], a0);
            a1 = fmaf(prod, w2[1][d], a1);
            a2 = fmaf(prod, w2[2][d], a2);
            a3 = fmaf(prod, w2[3][d], a3);
        }
        float adj = 0.25f * (a0 * rnorm[0][i] * rnorm[0][j] +
                             a1 * rnorm[1][i] * rnorm[1][j] +
                             a2 * rnorm[2][i] * rnorm[2][j] +
                             a3 * rnorm[3][i] * rnorm[3][j]);
        if (adj > EPSILON) {
            long long row = map_s[i];
            long long col = map_s[j];
            bucket_append(counts, entries, row * (long long)N_FULL + col, adj * rowscore);
        }
    }
}

// One block per 64 KB output chunk: zero LDS image, merge bucketed entries
// (LDS atomics handle duplicates), stream final values with NT float4 stores.
__global__ __launch_bounds__(256) void fill_merge_kernel(
        const int*   __restrict__ counts,
        const uint2* __restrict__ entries,
        float* __restrict__ out)
{
    __shared__ float img[CHUNK_FLOATS];      // 64 KB
    const int chunk = blockIdx.x;
    const int tid   = threadIdx.x;
    f4_t* img4 = (f4_t*)img;
    const f4_t z = (f4_t){0.f, 0.f, 0.f, 0.f};

    #pragma unroll
    for (int k = 0; k < CHUNK_FLOATS / 4 / 256; ++k)
        img4[tid + k * 256] = z;
    __syncthreads();

    int cnt = counts[chunk];
    if (cnt > CAP) cnt = CAP;
    for (int e = tid; e < cnt; e += 256) {
        uint2 en = entries[(size_t)chunk * CAP + e];
        atomicAdd(&img[en.x], __uint_as_float(en.y));
    }
    __syncthreads();

    f4_t* out4 = (f4_t*)out + (size_t)chunk * (CHUNK_FLOATS / 4);
    #pragma unroll
    for (int k = 0; k < CHUNK_FLOATS / 4 / 256; ++k)
        __builtin_nontemporal_store(img4[tid + k * 256], &out4[tid + k * 256]);
}

// ---------------- fallback path (R3): zero fill + atomic scatter ----------------
#define N4_TOTAL 37748736
#define FILL_BLOCKS 4096
#define PER_BLOCK (N4_TOTAL / FILL_BLOCKS)
#define FILL_ITERS (PER_BLOCK / 256)

__global__ __launch_bounds__(256) void zero_kernel(f4_t* __restrict__ out)
{
    size_t base = (size_t)blockIdx.x * PER_BLOCK + threadIdx.x;
    const f4_t z = (f4_t){0.f, 0.f, 0.f, 0.f};
    #pragma unroll
    for (int k = 0; k < FILL_ITERS; ++k)
        __builtin_nontemporal_store(z, &out[base + (size_t)k * 256]);
}

__global__ __launch_bounds__(256) void scatter_kernel(
        const float* __restrict__ x,
        const float* __restrict__ Wc,
        const float* __restrict__ sscore,
        const int*   __restrict__ smap,
        const int*   __restrict__ rei,
        float* __restrict__ out)
{
    const int tid = threadIdx.x;

    if (blockIdx.x >= N_SUB) {
        int e = (blockIdx.x - N_SUB) * 256 + tid;
        long long r = rei[e];
        long long c = rei[E_RAW + e];
        atomicAdd(&out[r * (long long)N_FULL + c], 1.0f - LAMB1);
        return;
    }

    const int s    = blockIdx.x;
    const int base = s * SUB_SZ;

    __shared__ float xs[SUB_SZ][D + 1];
    __shared__ float w2[N_PERS][D];
    __shared__ float rnorm[N_PERS][SUB_SZ];
    __shared__ int   map_s[SUB_SZ];
    __shared__ float rowscore;

    for (int k = tid; k < SUB_SZ * D; k += 256) {
        int i = k >> 7;
        int d = k & (D - 1);
        xs[i][d] = x[(base + i) * D + d];
    }
    for (int k = tid; k < N_PERS * D; k += 256) {
        float w = Wc[k];
        ((float*)w2)[k] = w * w;
    }
    if (tid < SUB_SZ) map_s[tid] = smap[base + tid];
    if (tid == 0) {
        int g4 = (s >> 2) << 2;
        float sum = sscore[g4] + sscore[g4 + 1] + sscore[g4 + 2] + sscore[g4 + 3];
        rowscore = (sscore[s] / sum) * LAMB1;
    }
    __syncthreads();

    if (tid < N_PERS * SUB_SZ) {
        int p = tid >> 5;
        int i = tid & 31;
        float acc = 0.f;
        #pragma unroll 8
        for (int d = 0; d < D; ++d) {
            float v = xs[i][d];
            acc = fmaf(v * v, w2[p][d], acc);
        }
        rnorm[p][i] = 1.0f / fmaxf(sqrtf(acc), 1e-12f);
    }
    __syncthreads();

    for (int e = tid; e < SUB_SZ * SUB_SZ; e += 256) {
        int i = e >> 5;
        int j = e & 31;
        if (i == j) continue;
        float a0 = 0.f, a1 = 0.f, a2 = 0.f, a3 = 0.f;
        #pragma unroll 8
        for (int d = 0; d < D; ++d) {
            float prod = xs[i][d] * xs[j][d];
            a0 = fmaf(prod, w2[0][d], a0);
            a1 = fmaf(prod, w2[1][d], a1);
            a2 = fmaf(prod, w2[2][d], a2);
            a3 = fmaf(prod, w2[3][d], a3);
        }
        float adj = 0.25f * (a0 * rnorm[0][i] * rnorm[0][j] +
                             a1 * rnorm[1][i] * rnorm[1][j] +
                             a2 * rnorm[2][i] * rnorm[2][j] +
                             a3 * rnorm[3][i] * rnorm[3][j]);
        if (adj > EPSILON) {
            long long row = map_s[i];
            long long col = map_s[j];
            atomicAdd(&out[row * (long long)N_FULL + col], adj * rowscore);
        }
    }
}

extern "C" void kernel_launch(void* const* d_in, const int* in_sizes, int n_in,
                              void* d_out, int out_size, void* d_ws, size_t ws_size,
                              hipStream_t stream) {
    const float* x      = (const float*)d_in[0];
    const float* Wc     = (const float*)d_in[1];
    const float* sscore = (const float*)d_in[2];
    const int* smap = (const int*)d_in[4];
    const int* rei  = (const int*)d_in[7];
    float* out = (float*)d_out;

    if (ws_size >= WS_NEEDED) {
        int*   counts  = (int*)d_ws;
        uint2* entries = (uint2*)((char*)d_ws + (size_t)N_CHUNKS * 4);

        zero_counts_kernel<<<(N_CHUNKS + 255) / 256, 256, 0, stream>>>(counts);
        build_kernel<<<N_SUB + E_RAW / 256, 256, 0, stream>>>(
            x, Wc, sscore, smap, rei, counts, entries);
        fill_merge_kernel<<<N_CHUNKS, 256, 0, stream>>>(counts, entries, out);
    } else {
        zero_kernel<<<FILL_BLOCKS, 256, 0, stream>>>((f4_t*)out);
        scatter_kernel<<<N_SUB + E_RAW / 256, 256, 0, stream>>>(
            x, Wc, sscore, smap, rei, out);
    }
}